// Round 15
// baseline (191.863 us; speedup 1.0000x reference)
//
#include <hip/hip_runtime.h>

// Chambolle-Pock anisotropic TV prox. B=8, H=W=256, 200 iters, fp32.
//
// Round 29 (session r14/r15): EXACT ASYNC PIPELINE (flags, no barrier).
// r15 = byte-identical resubmit of r14 (container failed twice = infra
// error class seen at r0 with a known-good kernel). Pre-registered: a
// SECOND identical failure => kernel hang => revert to r11 + disasm.
// r13's free-running async (drift limit 16) gave absmax 0.55 —
// staleness error is steep, so even staleness-2 is marginal. This
// round keeps EXACT synchronous values but drops the global barrier:
//  - ghost slots triple-buffered xb[3][NW+2][2][64] (slot (k+1)%3
//    receives ub^k); zero guard rows preserved;
//  - forward flags fl[NW+2] (volatile LDS, guards=INT_MAX): wave
//    enters iter k only when fl[w],fl[w+2] >= k (neighbors published
//    input-for-k). Bounds adjacent skew <= 1; slot-distance analysis:
//    earliest rewrite of slot k%3 is end of iter k+2, which requires
//    neighbors >= k+1, i.e., already done reading it -> race-free,
//    values identical to synchronous schedule. absmax MUST be exactly
//    0.01269531 (r11 bit pattern) — sharp discriminator.
//  - producer: ds_write data -> threadfence_block -> flag write;
//    consumer: spin -> threadfence_block -> ghost read (per-wave DS
//    program order makes flag-confirm imply data visibility).
//  - ghosts for iter k+1 prefetched at bottom of iter k; next q-
//    section (ghost-free) covers the LDS latency.
// Replaces ~500cyc 16-wave s_barrier convergence with a 2-flag poll
// that passes first time in steady state; waves pipeline-slide.
// Carried (r8-r12 validated): r11 geometry (16w x RPW=6, grid 7x4x8,
// 1 blk/CU best), T=200 single launch, H=12 halo, lane=col DPP
// wave_shl/shr horizontal, in-register vertical, boundary publishes
// right after their ub, med3-bounded edge garbage, OOB loads -> 0,
// row<256 store guard, waves_per_eu(4,4).

#define Hc 256
#define Wc 256
#define Bc 8

constexpr int Tl  = 200;     // all iterations in one launch
constexpr int HLc = 12;      // halo width
constexpr int RIr = 72;      // interior rows per block (96 - 2*12)
constexpr int RIc = 40;      // interior cols per block (64 - 2*12)
constexpr int NW  = 16;      // waves per block (1024 threads)
constexpr int RPW = 6;       // rows per wave (96 region rows / 16 waves)

constexpr float TAUc = 0.35355339f;
constexpr float SIGc = 0.35355339f;
constexpr float Ac_  = 1.0f / (1.0f + TAUc);
constexpr float Bq_  = TAUc * Ac_;

// clamp to [-b, b] in one v_med3_f32; NaN v -> -b (finite, 0 when b==0).
__device__ __forceinline__ float clipf(float v, float b) {
    return __builtin_amdgcn_fmed3f(v, -b, b);
}

// lane i <- lane i+1 (wave-wide); lane 63 -> 0.  WAVE_SHL1 = 0x130.
__device__ __forceinline__ float dpp_shl1(float x) {
    return __int_as_float(__builtin_amdgcn_update_dpp(
        0, __float_as_int(x), 0x130, 0xf, 0xf, true));
}
// lane i <- lane i-1 (wave-wide); lane 0 -> 0.  WAVE_SHR1 = 0x138.
__device__ __forceinline__ float dpp_shr1(float x) {
    return __int_as_float(__builtin_amdgcn_update_dpp(
        0, __float_as_int(x), 0x138, 0xf, 0xf, true));
}

__global__ __launch_bounds__(NW * 64)
__attribute__((amdgpu_waves_per_eu(4, 4)))
void tv_one(const float* __restrict__ f, const float* __restrict__ lam,
            float* __restrict__ fin_out)
{
    // triple-buffered ghost-row slots with zero guard rows.
    __shared__ float xb[3][NW + 2][2][64];
    // forward flags: fl[w+1] = highest iter whose INPUT wave w has
    // published. guards fl[0], fl[NW+1] = INT_MAX (always ready).
    volatile __shared__ int fl[NW + 2];

    const int t    = threadIdx.x;
    const int w    = t >> 6;          // wave 0..15 (row panel)
    const int lane = t & 63;          // region col
    const int tc   = blockIdx.x;      // 0..6
    const int tr   = blockIdx.y;      // 0..3
    const int b    = blockIdx.z;      // 0..7

    const int gi0 = tr * RIr - HLc;
    const int gj0 = tc * RIc - HLc;
    const int fr  = gi0 + w * RPW;    // first absolute row of this wave
    const int gj  = gj0 + lane;       // absolute col of this lane
    const bool colok = (unsigned)gj < 256u;
    const int boff = b * (Hc * Wc);

    float u[RPW], ub[RPW], p[RPW], q[RPW], bf[RPW], bp[RPW], bq[RPW];
    float pg, bpg;

    // ---- init: zero all 3 slots (guards included), init flags ----
    for (int idx = t; idx < 3 * (NW + 2) * 2 * 64; idx += NW * 64)
        ((float*)xb)[idx] = 0.f;
    if (t < NW + 2) fl[t] = (t == 0 || t == NW + 1) ? 0x7fffffff : -1;

    // ---------------- load phase ----------------
    #pragma unroll
    for (int i = 0; i < RPW; ++i) {
        const int row = fr + i;
        const bool rok = colok && (unsigned)row < 256u;
        const float fv = rok ? f[boff + (row << 8) + gj] : 0.f;
        bf[i] = Bq_ * fv;
        u[i]  = fv;
        ub[i] = fv;
        p[i]  = 0.f;
        q[i]  = 0.f;
    }
    pg = 0.f;
    #pragma unroll
    for (int i = 0; i < RPW; ++i) {
        const int row = fr + i;
        bp[i] = (colok && row >= 0 && row + 1 <= 255)
                    ? lam[boff + ((row + 1) << 8) + gj] : 0.f;
        bq[i] = (colok && (unsigned)row < 256u && gj + 1 <= 255)
                    ? lam[boff + (row << 8) + gj + 1] : 0.f;
    }
    bpg = (colok && fr - 1 >= 0 && fr <= 255) ? lam[boff + (fr << 8) + gj] : 0.f;

    __syncthreads();   // init visible; the ONLY block-wide barrier

    // ---------------- prologue publish (slot 0 = input for iter 0) ----------------
    xb[0][w + 1][0][lane] = ub[0];
    xb[0][w + 1][1][lane] = ub[RPW - 1];
    __threadfence_block();
    if (lane == 0) fl[w + 1] = 0;

    // prefetch ghosts for iter 0
    while (fl[w] < 0 || fl[w + 2] < 0) {}
    __threadfence_block();
    float ubT = xb[0][w][1][lane];
    float ubB = xb[0][w + 2][0][lane];

    int pslot = 1;   // slot (k+1)%3 for k=0

    // ---------------- 200 iterations (flag-pipelined, exact) ----------------
    for (int k = 0; k < Tl; ++k) {
        // ---- q updates (own rows only; right neighbor via DPP) ----
        #pragma unroll
        for (int i = 0; i < RPW; ++i) {
            const float ur = dpp_shl1(ub[i]);
            q[i] = clipf(fmaf(SIGc, ur - ub[i], q[i]), bq[i]);
        }
        // ---- p updates: interior first, ghost-dependent last ----
        #pragma unroll
        for (int i = 0; i < RPW - 1; ++i)
            p[i] = clipf(fmaf(SIGc, ub[i + 1] - ub[i], p[i]), bp[i]);
        pg = clipf(fmaf(SIGc, ub[0] - ubT, pg), bpg);
        p[RPW - 1] = clipf(fmaf(SIGc, ubB - ub[RPW - 1], p[RPW - 1]), bp[RPW - 1]);

        const bool pub = (k != Tl - 1);

        // ---- u, ubar: boundary rows first, published immediately ----
        {   // i = 0
            const float ql = dpp_shr1(q[0]);
            const float dv = (pg - p[0]) + (ql - q[0]);
            const float un = fmaf(-Bq_, dv, fmaf(Ac_, u[0], bf[0]));
            ub[0] = 2.f * un - u[0];
            u[0]  = un;
            if (pub) xb[pslot][w + 1][0][lane] = ub[0];
        }
        {   // i = RPW-1
            const float ql = dpp_shr1(q[RPW - 1]);
            const float dv = (p[RPW - 2] - p[RPW - 1]) + (ql - q[RPW - 1]);
            const float un = fmaf(-Bq_, dv, fmaf(Ac_, u[RPW - 1], bf[RPW - 1]));
            ub[RPW - 1] = 2.f * un - u[RPW - 1];
            u[RPW - 1]  = un;
            if (pub) xb[pslot][w + 1][1][lane] = ub[RPW - 1];
        }
        #pragma unroll
        for (int i = 1; i < RPW - 1; ++i) {
            const float ql = dpp_shr1(q[i]);
            const float dv = (p[i - 1] - p[i]) + (ql - q[i]);
            const float un = fmaf(-Bq_, dv, fmaf(Ac_, u[i], bf[i]));
            ub[i] = 2.f * un - u[i];
            u[i]  = un;
        }

        // ---- publish flag; wait neighbors; prefetch next ghosts ----
        if (pub) {
            __threadfence_block();           // data writes drained
            if (lane == 0) fl[w + 1] = k + 1;
            const int kk = k + 1;
            while (fl[w] < kk || fl[w + 2] < kk) {}
            __threadfence_block();           // no hoist of ghost reads
            ubT = xb[pslot][w][1][lane];
            ubB = xb[pslot][w + 2][0][lane];
            pslot = (pslot == 2) ? 0 : pslot + 1;
        }
    }

    // ---------------- store phase (interior only, image-clipped) ----------------
    const int istart = (HLc - w * RPW > 0) ? (HLc - w * RPW) : 0;
    const int iend_  = (HLc + RIr - w * RPW < RPW) ? (HLc + RIr - w * RPW) : RPW;
    const int cst = tc * RIc;
    const int cen = (cst + RIc < 256) ? (cst + RIc) : 256;
    const bool cin = (gj >= cst) && (gj < cen);

    #pragma unroll
    for (int i = 0; i < RPW; ++i) {
        const int row = fr + i;
        if (cin && i >= istart && i < iend_ && (unsigned)row < 256u) {
            fin_out[boff + (row << 8) + gj] = u[i];
        }
    }
}

extern "C" void kernel_launch(void* const* d_in, const int* in_sizes, int n_in,
                              void* d_out, int out_size, void* d_ws, size_t ws_size,
                              hipStream_t stream)
{
    const float* f   = (const float*)d_in[0];
    const float* lam = (const float*)d_in[1];

    dim3 grid(7, 4, 8);      // col-tiles x row-tiles x batch = 224 blocks
    dim3 blkd(NW * 64);      // 1024 threads = 16 waves

    tv_one<<<grid, blkd, 0, stream>>>(f, lam, (float*)d_out);
}

// Round 16
// 157.968 us; speedup vs baseline: 1.2146x; 1.2146x over previous
//
#include <hip/hip_runtime.h>

// Chambolle-Pock anisotropic TV prox. B=8, H=W=256, 200 iters, fp32.
//
// Round 30 (session r16): PACKED FP32 (v_pk_*) on the r11 baseline.
// r15 taught: stall ~470 is DS round-trip latency, NOT barrier
// convergence (flag version removed the barrier; stall unchanged,
// busy +410 from polls). r11's barrier is the cheapest exchange.
// Remaining lever = busy (960 cyc/iter vs ~720 ideal): use CDNA
// full-rate packed f32. Rows packed as float2 pairs (i, i+3):
//  - vertical neighbor of pair (i,i+3) = pair (i+1,i+4) = ub2[i+1]
//    for i=0,1; seam pair (3,6) = {ub2[0].y, ubB} (1 compose);
//  - u-section pprev: i=1,2 -> p2[i-1] exactly; i=0 -> {pg, p2[2].x};
//  - DPP applied per 32-bit half (cost/px unchanged);
//  - clip stays scalar v_med3 per element (no packed med3; 1/px same);
//  - a*b+c under hipcc default fp-contract=fast == fmaf bits.
// Per-2px instr 28 -> ~18 (0.64x): busy 960 -> ~620 cyc/iter.
// Geometry/protocol byte-identical r11 (best 121.5us): 16w x RPW=6,
// grid 7x4x8, guard-row zero xb, parity dbuf + unroll 2, 1 barrier/
// iter, T=200 single launch, H=12, med3-bounded edge garbage,
// OOB->0, row<256 store guard, waves_per_eu(4,4).
// Prediction: kernel ~95-108us, absmax exactly 0.01269531.
// Falsifier: busy/iter unchanged -> pk not emitted -> disasm round.

#define Hc 256
#define Wc 256
#define Bc 8

constexpr int Tl  = 200;     // all iterations in one launch
constexpr int HLc = 12;      // halo width
constexpr int RIr = 72;      // interior rows per block (96 - 2*12)
constexpr int RIc = 40;      // interior cols per block (64 - 2*12)
constexpr int NW  = 16;      // waves per block (1024 threads)
constexpr int RPW = 6;       // rows per wave (3 packed pairs)

constexpr float TAUc = 0.35355339f;
constexpr float SIGc = 0.35355339f;
constexpr float Ac_  = 1.0f / (1.0f + TAUc);
constexpr float Bq_  = TAUc * Ac_;

typedef float f2 __attribute__((ext_vector_type(2)));

// clamp to [-b, b] in one v_med3_f32; NaN v -> -b (finite, 0 when b==0).
__device__ __forceinline__ float clipf(float v, float b) {
    return __builtin_amdgcn_fmed3f(v, -b, b);
}
__device__ __forceinline__ f2 clip2(f2 v, f2 b) {
    return f2{__builtin_amdgcn_fmed3f(v.x, -b.x, b.x),
              __builtin_amdgcn_fmed3f(v.y, -b.y, b.y)};
}

// lane i <- lane i+1 (wave-wide); lane 63 -> 0.  WAVE_SHL1 = 0x130.
__device__ __forceinline__ float dpp_shl1(float x) {
    return __int_as_float(__builtin_amdgcn_update_dpp(
        0, __float_as_int(x), 0x130, 0xf, 0xf, true));
}
// lane i <- lane i-1 (wave-wide); lane 0 -> 0.  WAVE_SHR1 = 0x138.
__device__ __forceinline__ float dpp_shr1(float x) {
    return __int_as_float(__builtin_amdgcn_update_dpp(
        0, __float_as_int(x), 0x138, 0xf, 0xf, true));
}
__device__ __forceinline__ f2 dpp2_shl1(f2 v) {
    return f2{dpp_shl1(v.x), dpp_shl1(v.y)};
}
__device__ __forceinline__ f2 dpp2_shr1(f2 v) {
    return f2{dpp_shr1(v.x), dpp_shr1(v.y)};
}

__global__ __launch_bounds__(NW * 64)
__attribute__((amdgpu_waves_per_eu(4, 4)))
void tv_one(const float* __restrict__ f, const float* __restrict__ lam,
            float* __restrict__ fin_out)
{
    // parity-dbuf boundary-row exchange with ZERO GUARD ROWS:
    // wave w writes slot w+1; slots 0 and NW+1 stay zero forever.
    __shared__ float xb[2][NW + 2][2][64];

    const int t    = threadIdx.x;
    const int w    = t >> 6;          // wave 0..15 (row panel)
    const int lane = t & 63;          // region col
    const int tc   = blockIdx.x;      // 0..6
    const int tr   = blockIdx.y;      // 0..3
    const int b    = blockIdx.z;      // 0..7

    const int gi0 = tr * RIr - HLc;
    const int gj0 = tc * RIc - HLc;
    const int fr  = gi0 + w * RPW;    // first absolute row of this wave
    const int gj  = gj0 + lane;       // absolute col of this lane
    const bool colok = (unsigned)gj < 256u;
    const int boff = b * (Hc * Wc);

    // packed state: element pair = (row fr+i, row fr+i+3), i = 0..2
    f2 u2[3], ub2[3], p2[3], q2[3], bf2[3], bp2[3], bq2[3];
    float pg, bpg;

    // ---- zero entire xb once (guards of both parities included) ----
    for (int idx = t; idx < 2 * (NW + 2) * 2 * 64; idx += NW * 64)
        ((float*)xb)[idx] = 0.f;

    // ---------------- load phase ----------------
    auto ldrow = [&](int row, float& fv, float& bpv, float& bqv) {
        const bool rok = colok && (unsigned)row < 256u;
        fv  = rok ? f[boff + (row << 8) + gj] : 0.f;
        bpv = (colok && row >= 0 && row + 1 <= 255)
                  ? lam[boff + ((row + 1) << 8) + gj] : 0.f;
        bqv = (colok && (unsigned)row < 256u && gj + 1 <= 255)
                  ? lam[boff + (row << 8) + gj + 1] : 0.f;
    };
    #pragma unroll
    for (int i = 0; i < 3; ++i) {
        float fa, ba, qa, fb, bb, qb;
        ldrow(fr + i,     fa, ba, qa);
        ldrow(fr + i + 3, fb, bb, qb);
        u2[i]  = f2{fa, fb};
        ub2[i] = f2{fa, fb};
        bf2[i] = Bq_ * f2{fa, fb};
        bp2[i] = f2{ba, bb};
        bq2[i] = f2{qa, qb};
        p2[i]  = f2{0.f, 0.f};
        q2[i]  = f2{0.f, 0.f};
    }
    pg  = 0.f;
    bpg = (colok && fr - 1 >= 0 && fr <= 255) ? lam[boff + (fr << 8) + gj] : 0.f;

    // ---------------- prologue write (buf 0) ----------------
    xb[0][w + 1][0][lane] = ub2[0].x;     // row fr
    xb[0][w + 1][1][lane] = ub2[2].y;     // row fr+5
    __syncthreads();

    // ---------------- 200 iterations ----------------
    #pragma unroll 2
    for (int k = 0; k < Tl; ++k) {
        const int pb = k & 1;     // compile-time under unroll 2
        // raw reads (guard slots supply the 0 for w=0 / w=NW-1);
        // first consumer is the p-section — q-section covers latency.
        const float ubT = xb[pb][w][1][lane];
        const float ubB = xb[pb][w + 2][0][lane];

        // ---- q updates (prev-iter ub; right neighbor via DPP) ----
        #pragma unroll
        for (int i = 0; i < 3; ++i) {
            const f2 ur = dpp2_shl1(ub2[i]);
            q2[i] = clip2(q2[i] + SIGc * (ur - ub2[i]), bq2[i]);
        }
        // ---- p updates (vertical; packed pairs align with neighbors) ----
        p2[0] = clip2(p2[0] + SIGc * (ub2[1] - ub2[0]), bp2[0]);
        p2[1] = clip2(p2[1] + SIGc * (ub2[2] - ub2[1]), bp2[1]);
        {
            const f2 v3 = f2{ub2[0].y, ubB};   // rows (fr+3, fr+6)
            p2[2] = clip2(p2[2] + SIGc * (v3 - ub2[2]), bp2[2]);
        }
        pg = clipf(fmaf(SIGc, ub2[0].x - ubT, pg), bpg);

        // ---- u, ubar (left-neighbor q via DPP) ----
        {
            const f2 pprev = f2{pg, p2[2].x};      // rows (fr-1->pg, fr+2)
            const f2 ql = dpp2_shr1(q2[0]);
            const f2 dv = (pprev - p2[0]) + (ql - q2[0]);
            const f2 un = (Ac_ * u2[0] + bf2[0]) - Bq_ * dv;
            ub2[0] = 2.f * un - u2[0];
            u2[0]  = un;
        }
        #pragma unroll
        for (int i = 1; i < 3; ++i) {
            const f2 ql = dpp2_shr1(q2[i]);
            const f2 dv = (p2[i - 1] - p2[i]) + (ql - q2[i]);
            const f2 un = (Ac_ * u2[i] + bf2[i]) - Bq_ * dv;
            ub2[i] = 2.f * un - u2[i];
            u2[i]  = un;
        }

        // ---- publish boundary rows for next iter, then barrier ----
        if (k != Tl - 1) {
            xb[pb ^ 1][w + 1][0][lane] = ub2[0].x;
            xb[pb ^ 1][w + 1][1][lane] = ub2[2].y;
            __syncthreads();
        }
    }

    // ---------------- store phase (interior only, image-clipped) ----------------
    const int istart = (HLc - w * RPW > 0) ? (HLc - w * RPW) : 0;
    const int iend_  = (HLc + RIr - w * RPW < RPW) ? (HLc + RIr - w * RPW) : RPW;
    const int cst = tc * RIc;
    const int cen = (cst + RIc < 256) ? (cst + RIc) : 256;
    const bool cin = (gj >= cst) && (gj < cen);

    #pragma unroll
    for (int i = 0; i < RPW; ++i) {
        const int row = fr + i;
        if (cin && i >= istart && i < iend_ && (unsigned)row < 256u) {
            const float val = (i < 3) ? u2[i].x : u2[i - 3].y;
            fin_out[boff + (row << 8) + gj] = val;
        }
    }
}

extern "C" void kernel_launch(void* const* d_in, const int* in_sizes, int n_in,
                              void* d_out, int out_size, void* d_ws, size_t ws_size,
                              hipStream_t stream)
{
    const float* f   = (const float*)d_in[0];
    const float* lam = (const float*)d_in[1];

    dim3 grid(7, 4, 8);      // col-tiles x row-tiles x batch = 224 blocks
    dim3 blkd(NW * 64);      // 1024 threads = 16 waves

    tv_one<<<grid, blkd, 0, stream>>>(f, lam, (float*)d_out);
}